// Round 14
// baseline (582.094 us; speedup 1.0000x reference)
//
#include <hip/hip_runtime.h>
#include <cstdint>
#include <cstddef>

// ---------------------------------------------------------------------------
// BurnoutGAT round 14: round-13 (521us validated) + fuse k6(BN+ELU) into k7
// and restructure the [N,256]@[256,64] GEMM. Evidence: k7 was 109us with
// VALUBusy 29%, HBM 4.5% -- latency-bound on per-FMA global W2 loads.
// Fix: W2 in LDS (64KB), 8-row register blocking (8 FMA per W2s read),
// BN scale/bias applied during row staging (k6's 102MB o1 round-trip gone).
// ---------------------------------------------------------------------------

#define NEG_SLOPE 0.2f
#define BN_EPS 1e-5f

// KP: project attention vectors through W1: CS/CD[13][4]
__global__ __launch_bounds__(64) void kp_proj(
    const float* __restrict__ W1, const float* __restrict__ att_src1,
    const float* __restrict__ att_dst1, float* __restrict__ CS,
    float* __restrict__ CD) {
  int t = threadIdx.x;
  if (t >= 52) return;
  int k = t >> 2, h = t & 3;
  float cs = 0.f, cd = 0.f;
#pragma unroll 8
  for (int c = 0; c < 64; ++c) {
    float w = W1[k * 256 + h * 64 + c];
    cs = fmaf(w, att_src1[h * 64 + c], cs);
    cd = fmaf(w, att_dst1[h * 64 + c], cd);
  }
  CS[k * 4 + h] = cs;
  CD[k * 4 + h] = cd;
}

// KA: per-node logits from x directly
__global__ __launch_bounds__(256) void ka_logits(
    const float* __restrict__ x, const float* __restrict__ CS,
    const float* __restrict__ CD, float* __restrict__ as1,
    float* __restrict__ ad1, int N) {
  int n = blockIdx.x * blockDim.x + threadIdx.x;
  if (n >= N) return;
  float xr[13];
#pragma unroll
  for (int k = 0; k < 13; ++k) xr[k] = x[(size_t)n * 13 + k];
#pragma unroll
  for (int h = 0; h < 4; ++h) {
    float as = 0.f, ad = 0.f;
#pragma unroll
    for (int k = 0; k < 13; ++k) {
      as = fmaf(xr[k], CS[k * 4 + h], as);
      ad = fmaf(xr[k], CD[k * 4 + h], ad);
    }
    as1[(size_t)n * 4 + h] = as;
    ad1[(size_t)n * 4 + h] = ad;
  }
}

// CSR build 1: in-degree histogram (incl. self loops). curs must be 0.
__global__ void kc_hist(const int* __restrict__ dst, int* __restrict__ curs,
                        int E, int Et) {
  int e = blockIdx.x * blockDim.x + threadIdx.x;
  if (e >= Et) return;
  int d = (e < E) ? dst[e] : (e - E);
  atomicAdd(&curs[d], 1);
}

// CSR scan pass 1: per-block exclusive scan of curs -> rowptr (block-local);
// block totals -> blocksum.
__global__ __launch_bounds__(1024) void kc_scan1(
    const int* __restrict__ curs, int* __restrict__ rowptr,
    int* __restrict__ blocksum, int N) {
  __shared__ int sdata[1024];
  int t = threadIdx.x;
  int gid = blockIdx.x * 1024 + t;
  int v = (gid < N) ? curs[gid] : 0;
  sdata[t] = v;
  __syncthreads();
  for (int o = 1; o < 1024; o <<= 1) {
    int u = (t >= o) ? sdata[t - o] : 0;
    __syncthreads();
    sdata[t] += u;
    __syncthreads();
  }
  if (gid < N) rowptr[gid] = sdata[t] - v;  // exclusive within block
  if (t == 1023) blocksum[blockIdx.x] = sdata[1023];
}

// CSR scan pass 2: exclusive scan of blocksum[NB] in place (NB <= 1024).
__global__ __launch_bounds__(1024) void kc_scan2(int* __restrict__ blocksum,
                                                 int NB) {
  __shared__ int sd[1024];
  int t = threadIdx.x;
  int v = (t < NB) ? blocksum[t] : 0;
  sd[t] = v;
  __syncthreads();
  for (int o = 1; o < 1024; o <<= 1) {
    int u = (t >= o) ? sd[t - o] : 0;
    __syncthreads();
    sd[t] += u;
    __syncthreads();
  }
  if (t < NB) blocksum[t] = sd[t] - v;
}

// CSR scan pass 3: add block offsets; write rowptr + curs (cursor copy).
__global__ __launch_bounds__(1024) void kc_scan3(
    int* __restrict__ rowptr, int* __restrict__ curs,
    const int* __restrict__ blocksum, int N, int Et) {
  int gid = blockIdx.x * 1024 + threadIdx.x;
  if (gid < N) {
    int val = rowptr[gid] + blocksum[blockIdx.x];
    rowptr[gid] = val;
    curs[gid] = val;
  }
  if (gid == 0) rowptr[N] = Et;
}

// CSR build 3: scatter src ids into dst-sorted order.
__global__ void kc_scatter(const int* __restrict__ src, const int* __restrict__ dst,
                           int* __restrict__ curs, int* __restrict__ csrs,
                           int E, int Et) {
  int e = blockIdx.x * blockDim.x + threadIdx.x;
  if (e >= Et) return;
  int s, d;
  if (e < E) { s = src[e]; d = dst[e]; } else { s = d = e - E; }
  int pos = atomicAdd(&curs[d], 1);
  csrs[pos] = s;
}

// agg_x: y[d][h][k] = softmax-weighted sum of x[s][k] over in-edges of d.
__global__ __launch_bounds__(256) void agg_x(
    const float* __restrict__ x, const float* __restrict__ as1,
    const float* __restrict__ ad1, const int* __restrict__ rowptr,
    const int* __restrict__ csrs, float* __restrict__ y, int N) {
  int wv = threadIdx.x >> 6, lane = threadIdx.x & 63;
  int d = blockIdx.x * 4 + wv;
  if (d >= N) return;
  int r0 = rowptr[d], r1 = rowptr[d + 1];
  float4 adv = *(const float4*)(ad1 + (size_t)d * 4);
  int hh = lane / 13;
  int kk = lane - hh * 13;
  float acc = 0.f;
  float s0 = 0.f, s1 = 0.f, s2 = 0.f, s3 = 0.f;
  for (int base = r0; base < r1; base += 64) {
    int cd = min(64, r1 - base);
    int s = 0;
    float e0 = 0.f, e1 = 0.f, e2 = 0.f, e3 = 0.f;
    if (lane < cd) {
      s = csrs[base + lane];
      float4 av = *(const float4*)(as1 + (size_t)s * 4);
      float l0 = av.x + adv.x; l0 = l0 >= 0.f ? l0 : NEG_SLOPE * l0;
      float l1 = av.y + adv.y; l1 = l1 >= 0.f ? l1 : NEG_SLOPE * l1;
      float l2 = av.z + adv.z; l2 = l2 >= 0.f ? l2 : NEG_SLOPE * l2;
      float l3 = av.w + adv.w; l3 = l3 >= 0.f ? l3 : NEG_SLOPE * l3;
      e0 = __expf(l0); e1 = __expf(l1); e2 = __expf(l2); e3 = __expf(l3);
      s0 += e0; s1 += e1; s2 += e2; s3 += e3;
    }
    for (int k = 0; k < cd; ++k) {
      int sk = __shfl(s, k);
      float w0 = __shfl(e0, k), w1 = __shfl(e1, k);
      float w2 = __shfl(e2, k), w3 = __shfl(e3, k);
      float w = hh == 0 ? w0 : hh == 1 ? w1 : hh == 2 ? w2 : w3;
      float xv = (lane < 52) ? x[(size_t)sk * 13 + kk] : 0.f;
      acc = fmaf(w, xv, acc);
    }
  }
#pragma unroll
  for (int m = 32; m; m >>= 1) {
    s0 += __shfl_xor(s0, m); s1 += __shfl_xor(s1, m);
    s2 += __shfl_xor(s2, m); s3 += __shfl_xor(s3, m);
  }
  if (lane < 52) {
    float den = hh == 0 ? s0 : hh == 1 ? s1 : hh == 2 ? s2 : s3;
    y[(size_t)d * 52 + lane] = acc / den;
  }
}

// k1b: o1[n, h*64+c] = sum_k y[n][h][k] * W1[k, h*64+c]; W1 in LDS.
// Fused BN-stats epilogue.
__global__ __launch_bounds__(256) void k1b_dense(
    const float* __restrict__ y, const float* __restrict__ W1,
    float* __restrict__ o1, float* __restrict__ bnsum,
    float* __restrict__ bnsq, int N) {
  __shared__ float W1s[13 * 256];
  int f = threadIdx.x;
  for (int idx = f; idx < 13 * 256; idx += 256) W1s[idx] = W1[idx];
  __syncthreads();
  int w = f >> 6, lane = f & 63;
  float s = 0.f, sq = 0.f;
  for (int n = blockIdx.x; n < N; n += gridDim.x) {
    float yv = (lane < 13) ? y[(size_t)n * 52 + w * 13 + lane] : 0.f;
    float acc = 0.f;
#pragma unroll
    for (int k = 0; k < 13; ++k)
      acc = fmaf(__shfl(yv, k), W1s[k * 256 + f], acc);
    o1[(size_t)n * 256 + f] = acc;
    s += acc;
    sq += acc * acc;
  }
  unsafeAtomicAdd(&bnsum[f], s);
  unsafeAtomicAdd(&bnsq[f], sq);
}

// k67: fused BN(batch stats)+ELU+GEMM. h2 = ELU(BN(o1raw)) @ W2 [N,64],
// plus per-node attention logits a_src2/a_dst2 [N,2].
// W2 staged in LDS [256][64]; BN scale/bias in LDS; 32 rows per block-iter,
// 8 rows per wave with 8 register accumulators (8 FMA per W2s read).
__global__ __launch_bounds__(256) void k67_bn_gemm(
    const float* __restrict__ o1raw, const float* __restrict__ bnsum,
    const float* __restrict__ bnsq, const float* __restrict__ gamma,
    const float* __restrict__ beta, const float* __restrict__ W2,
    const float* __restrict__ att_src2, const float* __restrict__ att_dst2,
    float* __restrict__ h2, float* __restrict__ a_src2,
    float* __restrict__ a_dst2, int N, float invN) {
  __shared__ float W2s[256 * 64];   // 64KB [k][c]
  __shared__ float sb[2][256];      // BN scale, bias
  __shared__ float rows[32][256];   // 32KB BN'd+ELU'd rows
  int t = threadIdx.x;
  for (int idx = t; idx < 256 * 64; idx += 256) W2s[idx] = W2[idx];
  {
    float mu = bnsum[t] * invN;
    float var = bnsq[t] * invN - mu * mu;
    float sc = rsqrtf(var + BN_EPS) * gamma[t];
    sb[0][t] = sc;
    sb[1][t] = beta[t] - mu * sc;
  }
  __syncthreads();
  int wv = t >> 6, lane = t & 63;
  int g = lane >> 5, c = lane & 31;
  float asv = att_src2[lane];  // [2][32] flat == lane
  float adv = att_dst2[lane];
  for (int base = blockIdx.x * 32; base < N; base += gridDim.x * 32) {
    // stage 32 rows, BN+ELU applied on load
    for (int idx = t; idx < 32 * 256; idx += 256) {
      int r = idx >> 8, f = idx & 255;
      int n = base + r;
      float v = 0.f;
      if (n < N) {
        v = fmaf(o1raw[(size_t)n * 256 + f], sb[0][f], sb[1][f]);
        v = v > 0.f ? v : expm1f(v);
      }
      rows[r][f] = v;
    }
    __syncthreads();
    const float* r0 = rows[8 * wv + 0];
    const float* r1 = rows[8 * wv + 1];
    const float* r2 = rows[8 * wv + 2];
    const float* r3 = rows[8 * wv + 3];
    const float* r4 = rows[8 * wv + 4];
    const float* r5 = rows[8 * wv + 5];
    const float* r6 = rows[8 * wv + 6];
    const float* r7 = rows[8 * wv + 7];
    float a0 = 0.f, a1 = 0.f, a2 = 0.f, a3 = 0.f;
    float a4 = 0.f, a5 = 0.f, a6 = 0.f, a7 = 0.f;
#pragma unroll 4
    for (int k = 0; k < 256; ++k) {
      float w2v = W2s[k * 64 + lane];
      a0 = fmaf(r0[k], w2v, a0);
      a1 = fmaf(r1[k], w2v, a1);
      a2 = fmaf(r2[k], w2v, a2);
      a3 = fmaf(r3[k], w2v, a3);
      a4 = fmaf(r4[k], w2v, a4);
      a5 = fmaf(r5[k], w2v, a5);
      a6 = fmaf(r6[k], w2v, a6);
      a7 = fmaf(r7[k], w2v, a7);
    }
#pragma unroll
    for (int r = 0; r < 8; ++r) {
      float acc = r == 0 ? a0 : r == 1 ? a1 : r == 2 ? a2 : r == 3 ? a3
                : r == 4 ? a4 : r == 5 ? a5 : r == 6 ? a6 : a7;
      int n = base + 8 * wv + r;
      if (n < N) {
        h2[(size_t)n * 64 + lane] = acc;
        float ps = acc * asv;
        float pd = acc * adv;
#pragma unroll
        for (int m = 16; m; m >>= 1) {
          ps += __shfl_xor(ps, m);
          pd += __shfl_xor(pd, m);
        }
        if (c == 0) {
          a_src2[(size_t)n * 2 + g] = ps;
          a_dst2[(size_t)n * 2 + g] = pd;
        }
      }
    }
    __syncthreads();
  }
}

// Fused layer-2 aggregate + head-mean + b2 + ELU + Wc dot + bc.
__global__ __launch_bounds__(256) void kagg2_head(
    const float* __restrict__ h2, const float* __restrict__ as2,
    const float* __restrict__ ad2, const int* __restrict__ rowptr,
    const int* __restrict__ csrs, const float* __restrict__ b2,
    const float* __restrict__ Wc, const float* __restrict__ bc,
    float* __restrict__ out, int N) {
  int wv = threadIdx.x >> 6, lane = threadIdx.x & 63;
  int d = blockIdx.x * 4 + wv;
  if (d >= N) return;
  int r0 = rowptr[d], r1 = rowptr[d + 1];
  float2 adv = *(const float2*)(ad2 + (size_t)d * 2);
  int head = lane >> 5;
  float fa = 0.f, s0 = 0.f, s1 = 0.f;
  for (int base = r0; base < r1; base += 64) {
    int cd = min(64, r1 - base);
    int s = 0;
    float e0 = 0.f, e1 = 0.f;
    if (lane < cd) {
      s = csrs[base + lane];
      float2 av = *(const float2*)(as2 + (size_t)s * 2);
      float l0 = av.x + adv.x; l0 = l0 >= 0.f ? l0 : NEG_SLOPE * l0;
      float l1 = av.y + adv.y; l1 = l1 >= 0.f ? l1 : NEG_SLOPE * l1;
      e0 = __expf(l0); e1 = __expf(l1);
      s0 += e0; s1 += e1;
    }
    for (int k = 0; k < cd; ++k) {
      int sk = __shfl(s, k);
      float w0 = __shfl(e0, k), w1 = __shfl(e1, k);
      float v = h2[(size_t)sk * 64 + lane];
      fa = fmaf(head ? w1 : w0, v, fa);
    }
  }
#pragma unroll
  for (int m = 32; m; m >>= 1) {
    s0 += __shfl_xor(s0, m);
    s1 += __shfl_xor(s1, m);
  }
  float o2v = fa / (head ? s1 : s0);
  float partner = __shfl_xor(o2v, 32);
  if (lane < 32) {
    float m = 0.5f * (o2v + partner) + b2[lane];
    m = m > 0.f ? m : expm1f(m);
    float t = m * Wc[lane];
#pragma unroll
    for (int mk = 16; mk; mk >>= 1) t += __shfl_xor(t, mk);
    if (lane == 0) out[d] = t + bc[0];
  }
}

extern "C" void kernel_launch(void* const* d_in, const int* in_sizes, int n_in,
                              void* d_out, int out_size, void* d_ws, size_t ws_size,
                              hipStream_t stream) {
  const float* x = (const float*)d_in[0];
  const int* ei = (const int*)d_in[1];
  const float* W1 = (const float*)d_in[2];
  const float* as1w = (const float*)d_in[3];
  const float* ad1w = (const float*)d_in[4];
  // d_in[5] = b1: cancels exactly under BatchNorm -> unused
  const float* gamma1 = (const float*)d_in[6];
  const float* beta1 = (const float*)d_in[7];
  const float* W2 = (const float*)d_in[8];
  const float* as2w = (const float*)d_in[9];
  const float* ad2w = (const float*)d_in[10];
  const float* b2 = (const float*)d_in[11];
  const float* Wc = (const float*)d_in[12];
  const float* bc = (const float*)d_in[13];

  const int N = in_sizes[0] / 13;
  const int E = in_sizes[1] / 2;
  const int Et = E + N;  // + self loops
  const int* srcp = ei;
  const int* dstp = ei + E;

  float* ws = (float*)d_ws;
  float* O1 = ws;                                // N*256 (raw, pre-BN)
  float* Y = O1 + (size_t)N * 256;               // N*52
  float* AS1 = Y + (size_t)N * 52;               // N*4 (16B aligned)
  float* AD1 = AS1 + (size_t)N * 4;              // N*4
  float* H2 = AD1 + (size_t)N * 4;               // N*64
  float* AS2 = H2 + (size_t)N * 64;              // N*2
  float* AD2 = AS2 + (size_t)N * 2;              // N*2
  float* CS = AD2 + (size_t)N * 2;               // 64 (52 used)
  float* CD = CS + 64;                           // 64
  float* BNS = CD + 64;                          // 256
  float* BNQ = BNS + 256;                        // 256
  int* ROWPTR = (int*)(BNQ + 256);               // N+1
  int* CURS = ROWPTR + (N + 1);                  // N
  int* CSRS = CURS + N;                          // Et
  int* BLKSUM = CSRS + Et;                       // <=1024

  // zero the atomic accumulators (ws is re-poisoned before every launch)
  hipMemsetAsync(CURS, 0, (size_t)N * sizeof(int), stream);
  hipMemsetAsync(BNS, 0, 512 * sizeof(float), stream);

  int eb = (Et + 255) / 256;
  int nbs = (N + 1023) / 1024;
  // CSR build (shared by both layers); hierarchical 3-pass scan
  kc_hist<<<eb, 256, 0, stream>>>(dstp, CURS, E, Et);
  kc_scan1<<<nbs, 1024, 0, stream>>>(CURS, ROWPTR, BLKSUM, N);
  kc_scan2<<<1, 1024, 0, stream>>>(BLKSUM, nbs);
  kc_scan3<<<nbs, 1024, 0, stream>>>(ROWPTR, CURS, BLKSUM, N, Et);
  kc_scatter<<<eb, 256, 0, stream>>>(srcp, dstp, CURS, CSRS, E, Et);

  // layer 1 (h1 never materialized)
  kp_proj<<<1, 64, 0, stream>>>(W1, as1w, ad1w, CS, CD);
  ka_logits<<<(N + 255) / 256, 256, 0, stream>>>(x, CS, CD, AS1, AD1, N);
  agg_x<<<(N + 3) / 4, 256, 0, stream>>>(x, AS1, AD1, ROWPTR, CSRS, Y, N);
  k1b_dense<<<256, 256, 0, stream>>>(Y, W1, O1, BNS, BNQ, N);

  // layer 2: fused BN+ELU+GEMM (k6 eliminated)
  k67_bn_gemm<<<256, 256, 0, stream>>>(O1, BNS, BNQ, gamma1, beta1, W2,
                                       as2w, ad2w, H2, AS2, AD2, N,
                                       1.0f / (float)N);
  kagg2_head<<<(N + 3) / 4, 256, 0, stream>>>(H2, AS2, AD2, ROWPTR, CSRS,
                                              b2, Wc, bc, (float*)d_out, N);
}

// Round 15
// 470.400 us; speedup vs baseline: 1.2374x; 1.2374x over previous
//
#include <hip/hip_runtime.h>
#include <cstdint>
#include <cstddef>

// ---------------------------------------------------------------------------
// BurnoutGAT round 15: fix round-14's occupancy regression. k67 kept the
// BN+ELU+GEMM fusion but drops the 64KB W2 LDS tile (98KB LDS -> 10% occ ->
// 181us). W2 now read from global (L2-resident, 8 FMA per coalesced load via
// 8-row register blocking); LDS = 34KB (rows+sb) -> 4 blocks/CU, ~50% occ.
// ---------------------------------------------------------------------------

#define NEG_SLOPE 0.2f
#define BN_EPS 1e-5f

// KP: project attention vectors through W1: CS/CD[13][4]
__global__ __launch_bounds__(64) void kp_proj(
    const float* __restrict__ W1, const float* __restrict__ att_src1,
    const float* __restrict__ att_dst1, float* __restrict__ CS,
    float* __restrict__ CD) {
  int t = threadIdx.x;
  if (t >= 52) return;
  int k = t >> 2, h = t & 3;
  float cs = 0.f, cd = 0.f;
#pragma unroll 8
  for (int c = 0; c < 64; ++c) {
    float w = W1[k * 256 + h * 64 + c];
    cs = fmaf(w, att_src1[h * 64 + c], cs);
    cd = fmaf(w, att_dst1[h * 64 + c], cd);
  }
  CS[k * 4 + h] = cs;
  CD[k * 4 + h] = cd;
}

// KA: per-node logits from x directly
__global__ __launch_bounds__(256) void ka_logits(
    const float* __restrict__ x, const float* __restrict__ CS,
    const float* __restrict__ CD, float* __restrict__ as1,
    float* __restrict__ ad1, int N) {
  int n = blockIdx.x * blockDim.x + threadIdx.x;
  if (n >= N) return;
  float xr[13];
#pragma unroll
  for (int k = 0; k < 13; ++k) xr[k] = x[(size_t)n * 13 + k];
#pragma unroll
  for (int h = 0; h < 4; ++h) {
    float as = 0.f, ad = 0.f;
#pragma unroll
    for (int k = 0; k < 13; ++k) {
      as = fmaf(xr[k], CS[k * 4 + h], as);
      ad = fmaf(xr[k], CD[k * 4 + h], ad);
    }
    as1[(size_t)n * 4 + h] = as;
    ad1[(size_t)n * 4 + h] = ad;
  }
}

// CSR build 1: in-degree histogram (incl. self loops). curs must be 0.
__global__ void kc_hist(const int* __restrict__ dst, int* __restrict__ curs,
                        int E, int Et) {
  int e = blockIdx.x * blockDim.x + threadIdx.x;
  if (e >= Et) return;
  int d = (e < E) ? dst[e] : (e - E);
  atomicAdd(&curs[d], 1);
}

// CSR scan pass 1
__global__ __launch_bounds__(1024) void kc_scan1(
    const int* __restrict__ curs, int* __restrict__ rowptr,
    int* __restrict__ blocksum, int N) {
  __shared__ int sdata[1024];
  int t = threadIdx.x;
  int gid = blockIdx.x * 1024 + t;
  int v = (gid < N) ? curs[gid] : 0;
  sdata[t] = v;
  __syncthreads();
  for (int o = 1; o < 1024; o <<= 1) {
    int u = (t >= o) ? sdata[t - o] : 0;
    __syncthreads();
    sdata[t] += u;
    __syncthreads();
  }
  if (gid < N) rowptr[gid] = sdata[t] - v;
  if (t == 1023) blocksum[blockIdx.x] = sdata[1023];
}

// CSR scan pass 2
__global__ __launch_bounds__(1024) void kc_scan2(int* __restrict__ blocksum,
                                                 int NB) {
  __shared__ int sd[1024];
  int t = threadIdx.x;
  int v = (t < NB) ? blocksum[t] : 0;
  sd[t] = v;
  __syncthreads();
  for (int o = 1; o < 1024; o <<= 1) {
    int u = (t >= o) ? sd[t - o] : 0;
    __syncthreads();
    sd[t] += u;
    __syncthreads();
  }
  if (t < NB) blocksum[t] = sd[t] - v;
}

// CSR scan pass 3
__global__ __launch_bounds__(1024) void kc_scan3(
    int* __restrict__ rowptr, int* __restrict__ curs,
    const int* __restrict__ blocksum, int N, int Et) {
  int gid = blockIdx.x * 1024 + threadIdx.x;
  if (gid < N) {
    int val = rowptr[gid] + blocksum[blockIdx.x];
    rowptr[gid] = val;
    curs[gid] = val;
  }
  if (gid == 0) rowptr[N] = Et;
}

// CSR build 3: scatter src ids into dst-sorted order.
__global__ void kc_scatter(const int* __restrict__ src, const int* __restrict__ dst,
                           int* __restrict__ curs, int* __restrict__ csrs,
                           int E, int Et) {
  int e = blockIdx.x * blockDim.x + threadIdx.x;
  if (e >= Et) return;
  int s, d;
  if (e < E) { s = src[e]; d = dst[e]; } else { s = d = e - E; }
  int pos = atomicAdd(&curs[d], 1);
  csrs[pos] = s;
}

// agg_x: y[d][h][k] = softmax-weighted sum of x[s][k] over in-edges of d.
__global__ __launch_bounds__(256) void agg_x(
    const float* __restrict__ x, const float* __restrict__ as1,
    const float* __restrict__ ad1, const int* __restrict__ rowptr,
    const int* __restrict__ csrs, float* __restrict__ y, int N) {
  int wv = threadIdx.x >> 6, lane = threadIdx.x & 63;
  int d = blockIdx.x * 4 + wv;
  if (d >= N) return;
  int r0 = rowptr[d], r1 = rowptr[d + 1];
  float4 adv = *(const float4*)(ad1 + (size_t)d * 4);
  int hh = lane / 13;
  int kk = lane - hh * 13;
  float acc = 0.f;
  float s0 = 0.f, s1 = 0.f, s2 = 0.f, s3 = 0.f;
  for (int base = r0; base < r1; base += 64) {
    int cd = min(64, r1 - base);
    int s = 0;
    float e0 = 0.f, e1 = 0.f, e2 = 0.f, e3 = 0.f;
    if (lane < cd) {
      s = csrs[base + lane];
      float4 av = *(const float4*)(as1 + (size_t)s * 4);
      float l0 = av.x + adv.x; l0 = l0 >= 0.f ? l0 : NEG_SLOPE * l0;
      float l1 = av.y + adv.y; l1 = l1 >= 0.f ? l1 : NEG_SLOPE * l1;
      float l2 = av.z + adv.z; l2 = l2 >= 0.f ? l2 : NEG_SLOPE * l2;
      float l3 = av.w + adv.w; l3 = l3 >= 0.f ? l3 : NEG_SLOPE * l3;
      e0 = __expf(l0); e1 = __expf(l1); e2 = __expf(l2); e3 = __expf(l3);
      s0 += e0; s1 += e1; s2 += e2; s3 += e3;
    }
    for (int k = 0; k < cd; ++k) {
      int sk = __shfl(s, k);
      float w0 = __shfl(e0, k), w1 = __shfl(e1, k);
      float w2 = __shfl(e2, k), w3 = __shfl(e3, k);
      float w = hh == 0 ? w0 : hh == 1 ? w1 : hh == 2 ? w2 : w3;
      float xv = (lane < 52) ? x[(size_t)sk * 13 + kk] : 0.f;
      acc = fmaf(w, xv, acc);
    }
  }
#pragma unroll
  for (int m = 32; m; m >>= 1) {
    s0 += __shfl_xor(s0, m); s1 += __shfl_xor(s1, m);
    s2 += __shfl_xor(s2, m); s3 += __shfl_xor(s3, m);
  }
  if (lane < 52) {
    float den = hh == 0 ? s0 : hh == 1 ? s1 : hh == 2 ? s2 : s3;
    y[(size_t)d * 52 + lane] = acc / den;
  }
}

// k1b: o1[n, h*64+c] = sum_k y[n][h][k] * W1[k, h*64+c]; W1 in LDS.
// Fused BN-stats epilogue.
__global__ __launch_bounds__(256) void k1b_dense(
    const float* __restrict__ y, const float* __restrict__ W1,
    float* __restrict__ o1, float* __restrict__ bnsum,
    float* __restrict__ bnsq, int N) {
  __shared__ float W1s[13 * 256];
  int f = threadIdx.x;
  for (int idx = f; idx < 13 * 256; idx += 256) W1s[idx] = W1[idx];
  __syncthreads();
  int w = f >> 6, lane = f & 63;
  float s = 0.f, sq = 0.f;
  for (int n = blockIdx.x; n < N; n += gridDim.x) {
    float yv = (lane < 13) ? y[(size_t)n * 52 + w * 13 + lane] : 0.f;
    float acc = 0.f;
#pragma unroll
    for (int k = 0; k < 13; ++k)
      acc = fmaf(__shfl(yv, k), W1s[k * 256 + f], acc);
    o1[(size_t)n * 256 + f] = acc;
    s += acc;
    sq += acc * acc;
  }
  unsafeAtomicAdd(&bnsum[f], s);
  unsafeAtomicAdd(&bnsq[f], sq);
}

// k67 v2: fused BN+ELU+GEMM, W2 from GLOBAL (L2-resident; 8 FMA per load).
// LDS: rows 32KB + sb 2KB -> 4 blocks/CU. Each block: 32 rows; each wave: 8
// rows x 64 cols with 8 register accumulators.
__global__ __launch_bounds__(256) void k67_bn_gemm(
    const float* __restrict__ o1raw, const float* __restrict__ bnsum,
    const float* __restrict__ bnsq, const float* __restrict__ gamma,
    const float* __restrict__ beta, const float* __restrict__ W2,
    const float* __restrict__ att_src2, const float* __restrict__ att_dst2,
    float* __restrict__ h2, float* __restrict__ a_src2,
    float* __restrict__ a_dst2, int N, float invN) {
  __shared__ float rows[32][256];   // 32KB BN'd+ELU'd rows
  __shared__ float sb[2][256];      // BN scale, bias
  int t = threadIdx.x;
  {
    float mu = bnsum[t] * invN;
    float var = bnsq[t] * invN - mu * mu;
    float sc = rsqrtf(var + BN_EPS) * gamma[t];
    sb[0][t] = sc;
    sb[1][t] = beta[t] - mu * sc;
  }
  __syncthreads();
  int wv = t >> 6, lane = t & 63;
  int g = lane >> 5, c = lane & 31;
  float asv = att_src2[lane];  // [2][32] flat == lane
  float adv = att_dst2[lane];
  int base = blockIdx.x * 32;
  // stage 32 rows, BN+ELU applied on load
  for (int idx = t; idx < 32 * 256; idx += 256) {
    int r = idx >> 8, f = idx & 255;
    int n = base + r;
    float v = 0.f;
    if (n < N) {
      v = fmaf(o1raw[(size_t)n * 256 + f], sb[0][f], sb[1][f]);
      v = v > 0.f ? v : expm1f(v);
    }
    rows[r][f] = v;
  }
  __syncthreads();
  const float* r0 = rows[8 * wv + 0];
  const float* r1 = rows[8 * wv + 1];
  const float* r2 = rows[8 * wv + 2];
  const float* r3 = rows[8 * wv + 3];
  const float* r4 = rows[8 * wv + 4];
  const float* r5 = rows[8 * wv + 5];
  const float* r6 = rows[8 * wv + 6];
  const float* r7 = rows[8 * wv + 7];
  float a0 = 0.f, a1 = 0.f, a2 = 0.f, a3 = 0.f;
  float a4 = 0.f, a5 = 0.f, a6 = 0.f, a7 = 0.f;
#pragma unroll 4
  for (int k = 0; k < 256; ++k) {
    float w2v = W2[k * 64 + lane];   // global, coalesced, L2-resident
    a0 = fmaf(r0[k], w2v, a0);
    a1 = fmaf(r1[k], w2v, a1);
    a2 = fmaf(r2[k], w2v, a2);
    a3 = fmaf(r3[k], w2v, a3);
    a4 = fmaf(r4[k], w2v, a4);
    a5 = fmaf(r5[k], w2v, a5);
    a6 = fmaf(r6[k], w2v, a6);
    a7 = fmaf(r7[k], w2v, a7);
  }
#pragma unroll
  for (int r = 0; r < 8; ++r) {
    float acc = r == 0 ? a0 : r == 1 ? a1 : r == 2 ? a2 : r == 3 ? a3
              : r == 4 ? a4 : r == 5 ? a5 : r == 6 ? a6 : a7;
    int n = base + 8 * wv + r;
    if (n < N) {
      h2[(size_t)n * 64 + lane] = acc;
      float ps = acc * asv;
      float pd = acc * adv;
#pragma unroll
      for (int m = 16; m; m >>= 1) {
        ps += __shfl_xor(ps, m);
        pd += __shfl_xor(pd, m);
      }
      if (c == 0) {
        a_src2[(size_t)n * 2 + g] = ps;
        a_dst2[(size_t)n * 2 + g] = pd;
      }
    }
  }
}

// Fused layer-2 aggregate + head-mean + b2 + ELU + Wc dot + bc.
__global__ __launch_bounds__(256) void kagg2_head(
    const float* __restrict__ h2, const float* __restrict__ as2,
    const float* __restrict__ ad2, const int* __restrict__ rowptr,
    const int* __restrict__ csrs, const float* __restrict__ b2,
    const float* __restrict__ Wc, const float* __restrict__ bc,
    float* __restrict__ out, int N) {
  int wv = threadIdx.x >> 6, lane = threadIdx.x & 63;
  int d = blockIdx.x * 4 + wv;
  if (d >= N) return;
  int r0 = rowptr[d], r1 = rowptr[d + 1];
  float2 adv = *(const float2*)(ad2 + (size_t)d * 2);
  int head = lane >> 5;
  float fa = 0.f, s0 = 0.f, s1 = 0.f;
  for (int base = r0; base < r1; base += 64) {
    int cd = min(64, r1 - base);
    int s = 0;
    float e0 = 0.f, e1 = 0.f;
    if (lane < cd) {
      s = csrs[base + lane];
      float2 av = *(const float2*)(as2 + (size_t)s * 2);
      float l0 = av.x + adv.x; l0 = l0 >= 0.f ? l0 : NEG_SLOPE * l0;
      float l1 = av.y + adv.y; l1 = l1 >= 0.f ? l1 : NEG_SLOPE * l1;
      e0 = __expf(l0); e1 = __expf(l1);
      s0 += e0; s1 += e1;
    }
    for (int k = 0; k < cd; ++k) {
      int sk = __shfl(s, k);
      float w0 = __shfl(e0, k), w1 = __shfl(e1, k);
      float v = h2[(size_t)sk * 64 + lane];
      fa = fmaf(head ? w1 : w0, v, fa);
    }
  }
#pragma unroll
  for (int m = 32; m; m >>= 1) {
    s0 += __shfl_xor(s0, m);
    s1 += __shfl_xor(s1, m);
  }
  float o2v = fa / (head ? s1 : s0);
  float partner = __shfl_xor(o2v, 32);
  if (lane < 32) {
    float m = 0.5f * (o2v + partner) + b2[lane];
    m = m > 0.f ? m : expm1f(m);
    float t = m * Wc[lane];
#pragma unroll
    for (int mk = 16; mk; mk >>= 1) t += __shfl_xor(t, mk);
    if (lane == 0) out[d] = t + bc[0];
  }
}

extern "C" void kernel_launch(void* const* d_in, const int* in_sizes, int n_in,
                              void* d_out, int out_size, void* d_ws, size_t ws_size,
                              hipStream_t stream) {
  const float* x = (const float*)d_in[0];
  const int* ei = (const int*)d_in[1];
  const float* W1 = (const float*)d_in[2];
  const float* as1w = (const float*)d_in[3];
  const float* ad1w = (const float*)d_in[4];
  // d_in[5] = b1: cancels exactly under BatchNorm -> unused
  const float* gamma1 = (const float*)d_in[6];
  const float* beta1 = (const float*)d_in[7];
  const float* W2 = (const float*)d_in[8];
  const float* as2w = (const float*)d_in[9];
  const float* ad2w = (const float*)d_in[10];
  const float* b2 = (const float*)d_in[11];
  const float* Wc = (const float*)d_in[12];
  const float* bc = (const float*)d_in[13];

  const int N = in_sizes[0] / 13;
  const int E = in_sizes[1] / 2;
  const int Et = E + N;  // + self loops
  const int* srcp = ei;
  const int* dstp = ei + E;

  float* ws = (float*)d_ws;
  float* O1 = ws;                                // N*256 (raw, pre-BN)
  float* Y = O1 + (size_t)N * 256;               // N*52
  float* AS1 = Y + (size_t)N * 52;               // N*4 (16B aligned)
  float* AD1 = AS1 + (size_t)N * 4;              // N*4
  float* H2 = AD1 + (size_t)N * 4;               // N*64
  float* AS2 = H2 + (size_t)N * 64;              // N*2
  float* AD2 = AS2 + (size_t)N * 2;              // N*2
  float* CS = AD2 + (size_t)N * 2;               // 64 (52 used)
  float* CD = CS + 64;                           // 64
  float* BNS = CD + 64;                          // 256
  float* BNQ = BNS + 256;                        // 256
  int* ROWPTR = (int*)(BNQ + 256);               // N+1
  int* CURS = ROWPTR + (N + 1);                  // N
  int* CSRS = CURS + N;                          // Et
  int* BLKSUM = CSRS + Et;                       // <=1024

  // zero the atomic accumulators (ws is re-poisoned before every launch)
  hipMemsetAsync(CURS, 0, (size_t)N * sizeof(int), stream);
  hipMemsetAsync(BNS, 0, 512 * sizeof(float), stream);

  int eb = (Et + 255) / 256;
  int nbs = (N + 1023) / 1024;
  // CSR build (shared by both layers); hierarchical 3-pass scan
  kc_hist<<<eb, 256, 0, stream>>>(dstp, CURS, E, Et);
  kc_scan1<<<nbs, 1024, 0, stream>>>(CURS, ROWPTR, BLKSUM, N);
  kc_scan2<<<1, 1024, 0, stream>>>(BLKSUM, nbs);
  kc_scan3<<<nbs, 1024, 0, stream>>>(ROWPTR, CURS, BLKSUM, N, Et);
  kc_scatter<<<eb, 256, 0, stream>>>(srcp, dstp, CURS, CSRS, E, Et);

  // layer 1 (h1 never materialized)
  kp_proj<<<1, 64, 0, stream>>>(W1, as1w, ad1w, CS, CD);
  ka_logits<<<(N + 255) / 256, 256, 0, stream>>>(x, CS, CD, AS1, AD1, N);
  agg_x<<<(N + 3) / 4, 256, 0, stream>>>(x, AS1, AD1, ROWPTR, CSRS, Y, N);
  k1b_dense<<<256, 256, 0, stream>>>(Y, W1, O1, BNS, BNQ, N);

  // layer 2: fused BN+ELU+GEMM (k6 eliminated), W2 from global
  k67_bn_gemm<<<(N + 31) / 32, 256, 0, stream>>>(O1, BNS, BNQ, gamma1, beta1,
                                                 W2, as2w, ad2w, H2, AS2, AD2,
                                                 N, 1.0f / (float)N);
  kagg2_head<<<(N + 3) / 4, 256, 0, stream>>>(H2, AS2, AD2, ROWPTR, CSRS,
                                              b2, Wc, bc, (float*)d_out, N);
}

// Round 16
// 442.413 us; speedup vs baseline: 1.3157x; 1.0633x over previous
//
#include <hip/hip_runtime.h>
#include <cstdint>
#include <cstddef>

// ---------------------------------------------------------------------------
// BurnoutGAT round 16: round-15 (470us validated) + fix k1b_dense occupancy.
// Evidence: k1b was 90.6us with grid=256 (1 block/CU, 1 wave/SIMD, occ 10%),
// VALUBusy 6%, HBM 8% -- pure exposed latency. Launch with grid=1024
// (4 blocks/CU, ~50% occ). No kernel-body changes.
// ---------------------------------------------------------------------------

#define NEG_SLOPE 0.2f
#define BN_EPS 1e-5f

// KP: project attention vectors through W1: CS/CD[13][4]
__global__ __launch_bounds__(64) void kp_proj(
    const float* __restrict__ W1, const float* __restrict__ att_src1,
    const float* __restrict__ att_dst1, float* __restrict__ CS,
    float* __restrict__ CD) {
  int t = threadIdx.x;
  if (t >= 52) return;
  int k = t >> 2, h = t & 3;
  float cs = 0.f, cd = 0.f;
#pragma unroll 8
  for (int c = 0; c < 64; ++c) {
    float w = W1[k * 256 + h * 64 + c];
    cs = fmaf(w, att_src1[h * 64 + c], cs);
    cd = fmaf(w, att_dst1[h * 64 + c], cd);
  }
  CS[k * 4 + h] = cs;
  CD[k * 4 + h] = cd;
}

// KA: per-node logits from x directly
__global__ __launch_bounds__(256) void ka_logits(
    const float* __restrict__ x, const float* __restrict__ CS,
    const float* __restrict__ CD, float* __restrict__ as1,
    float* __restrict__ ad1, int N) {
  int n = blockIdx.x * blockDim.x + threadIdx.x;
  if (n >= N) return;
  float xr[13];
#pragma unroll
  for (int k = 0; k < 13; ++k) xr[k] = x[(size_t)n * 13 + k];
#pragma unroll
  for (int h = 0; h < 4; ++h) {
    float as = 0.f, ad = 0.f;
#pragma unroll
    for (int k = 0; k < 13; ++k) {
      as = fmaf(xr[k], CS[k * 4 + h], as);
      ad = fmaf(xr[k], CD[k * 4 + h], ad);
    }
    as1[(size_t)n * 4 + h] = as;
    ad1[(size_t)n * 4 + h] = ad;
  }
}

// CSR build 1: in-degree histogram (incl. self loops). curs must be 0.
__global__ void kc_hist(const int* __restrict__ dst, int* __restrict__ curs,
                        int E, int Et) {
  int e = blockIdx.x * blockDim.x + threadIdx.x;
  if (e >= Et) return;
  int d = (e < E) ? dst[e] : (e - E);
  atomicAdd(&curs[d], 1);
}

// CSR scan pass 1
__global__ __launch_bounds__(1024) void kc_scan1(
    const int* __restrict__ curs, int* __restrict__ rowptr,
    int* __restrict__ blocksum, int N) {
  __shared__ int sdata[1024];
  int t = threadIdx.x;
  int gid = blockIdx.x * 1024 + t;
  int v = (gid < N) ? curs[gid] : 0;
  sdata[t] = v;
  __syncthreads();
  for (int o = 1; o < 1024; o <<= 1) {
    int u = (t >= o) ? sdata[t - o] : 0;
    __syncthreads();
    sdata[t] += u;
    __syncthreads();
  }
  if (gid < N) rowptr[gid] = sdata[t] - v;
  if (t == 1023) blocksum[blockIdx.x] = sdata[1023];
}

// CSR scan pass 2
__global__ __launch_bounds__(1024) void kc_scan2(int* __restrict__ blocksum,
                                                 int NB) {
  __shared__ int sd[1024];
  int t = threadIdx.x;
  int v = (t < NB) ? blocksum[t] : 0;
  sd[t] = v;
  __syncthreads();
  for (int o = 1; o < 1024; o <<= 1) {
    int u = (t >= o) ? sd[t - o] : 0;
    __syncthreads();
    sd[t] += u;
    __syncthreads();
  }
  if (t < NB) blocksum[t] = sd[t] - v;
}

// CSR scan pass 3
__global__ __launch_bounds__(1024) void kc_scan3(
    int* __restrict__ rowptr, int* __restrict__ curs,
    const int* __restrict__ blocksum, int N, int Et) {
  int gid = blockIdx.x * 1024 + threadIdx.x;
  if (gid < N) {
    int val = rowptr[gid] + blocksum[blockIdx.x];
    rowptr[gid] = val;
    curs[gid] = val;
  }
  if (gid == 0) rowptr[N] = Et;
}

// CSR build 3: scatter src ids into dst-sorted order.
__global__ void kc_scatter(const int* __restrict__ src, const int* __restrict__ dst,
                           int* __restrict__ curs, int* __restrict__ csrs,
                           int E, int Et) {
  int e = blockIdx.x * blockDim.x + threadIdx.x;
  if (e >= Et) return;
  int s, d;
  if (e < E) { s = src[e]; d = dst[e]; } else { s = d = e - E; }
  int pos = atomicAdd(&curs[d], 1);
  csrs[pos] = s;
}

// agg_x: y[d][h][k] = softmax-weighted sum of x[s][k] over in-edges of d.
__global__ __launch_bounds__(256) void agg_x(
    const float* __restrict__ x, const float* __restrict__ as1,
    const float* __restrict__ ad1, const int* __restrict__ rowptr,
    const int* __restrict__ csrs, float* __restrict__ y, int N) {
  int wv = threadIdx.x >> 6, lane = threadIdx.x & 63;
  int d = blockIdx.x * 4 + wv;
  if (d >= N) return;
  int r0 = rowptr[d], r1 = rowptr[d + 1];
  float4 adv = *(const float4*)(ad1 + (size_t)d * 4);
  int hh = lane / 13;
  int kk = lane - hh * 13;
  float acc = 0.f;
  float s0 = 0.f, s1 = 0.f, s2 = 0.f, s3 = 0.f;
  for (int base = r0; base < r1; base += 64) {
    int cd = min(64, r1 - base);
    int s = 0;
    float e0 = 0.f, e1 = 0.f, e2 = 0.f, e3 = 0.f;
    if (lane < cd) {
      s = csrs[base + lane];
      float4 av = *(const float4*)(as1 + (size_t)s * 4);
      float l0 = av.x + adv.x; l0 = l0 >= 0.f ? l0 : NEG_SLOPE * l0;
      float l1 = av.y + adv.y; l1 = l1 >= 0.f ? l1 : NEG_SLOPE * l1;
      float l2 = av.z + adv.z; l2 = l2 >= 0.f ? l2 : NEG_SLOPE * l2;
      float l3 = av.w + adv.w; l3 = l3 >= 0.f ? l3 : NEG_SLOPE * l3;
      e0 = __expf(l0); e1 = __expf(l1); e2 = __expf(l2); e3 = __expf(l3);
      s0 += e0; s1 += e1; s2 += e2; s3 += e3;
    }
    for (int k = 0; k < cd; ++k) {
      int sk = __shfl(s, k);
      float w0 = __shfl(e0, k), w1 = __shfl(e1, k);
      float w2 = __shfl(e2, k), w3 = __shfl(e3, k);
      float w = hh == 0 ? w0 : hh == 1 ? w1 : hh == 2 ? w2 : w3;
      float xv = (lane < 52) ? x[(size_t)sk * 13 + kk] : 0.f;
      acc = fmaf(w, xv, acc);
    }
  }
#pragma unroll
  for (int m = 32; m; m >>= 1) {
    s0 += __shfl_xor(s0, m); s1 += __shfl_xor(s1, m);
    s2 += __shfl_xor(s2, m); s3 += __shfl_xor(s3, m);
  }
  if (lane < 52) {
    float den = hh == 0 ? s0 : hh == 1 ? s1 : hh == 2 ? s2 : s3;
    y[(size_t)d * 52 + lane] = acc / den;
  }
}

// k1b: o1[n, h*64+c] = sum_k y[n][h][k] * W1[k, h*64+c]; W1 in LDS.
// Fused BN-stats epilogue.
__global__ __launch_bounds__(256) void k1b_dense(
    const float* __restrict__ y, const float* __restrict__ W1,
    float* __restrict__ o1, float* __restrict__ bnsum,
    float* __restrict__ bnsq, int N) {
  __shared__ float W1s[13 * 256];
  int f = threadIdx.x;
  for (int idx = f; idx < 13 * 256; idx += 256) W1s[idx] = W1[idx];
  __syncthreads();
  int w = f >> 6, lane = f & 63;
  float s = 0.f, sq = 0.f;
  for (int n = blockIdx.x; n < N; n += gridDim.x) {
    float yv = (lane < 13) ? y[(size_t)n * 52 + w * 13 + lane] : 0.f;
    float acc = 0.f;
#pragma unroll
    for (int k = 0; k < 13; ++k)
      acc = fmaf(__shfl(yv, k), W1s[k * 256 + f], acc);
    o1[(size_t)n * 256 + f] = acc;
    s += acc;
    sq += acc * acc;
  }
  unsafeAtomicAdd(&bnsum[f], s);
  unsafeAtomicAdd(&bnsq[f], sq);
}

// k67 v2: fused BN+ELU+GEMM, W2 from GLOBAL (L2-resident; 8 FMA per load).
__global__ __launch_bounds__(256) void k67_bn_gemm(
    const float* __restrict__ o1raw, const float* __restrict__ bnsum,
    const float* __restrict__ bnsq, const float* __restrict__ gamma,
    const float* __restrict__ beta, const float* __restrict__ W2,
    const float* __restrict__ att_src2, const float* __restrict__ att_dst2,
    float* __restrict__ h2, float* __restrict__ a_src2,
    float* __restrict__ a_dst2, int N, float invN) {
  __shared__ float rows[32][256];   // 32KB BN'd+ELU'd rows
  __shared__ float sb[2][256];      // BN scale, bias
  int t = threadIdx.x;
  {
    float mu = bnsum[t] * invN;
    float var = bnsq[t] * invN - mu * mu;
    float sc = rsqrtf(var + BN_EPS) * gamma[t];
    sb[0][t] = sc;
    sb[1][t] = beta[t] - mu * sc;
  }
  __syncthreads();
  int wv = t >> 6, lane = t & 63;
  int g = lane >> 5, c = lane & 31;
  float asv = att_src2[lane];  // [2][32] flat == lane
  float adv = att_dst2[lane];
  int base = blockIdx.x * 32;
  // stage 32 rows, BN+ELU applied on load
  for (int idx = t; idx < 32 * 256; idx += 256) {
    int r = idx >> 8, f = idx & 255;
    int n = base + r;
    float v = 0.f;
    if (n < N) {
      v = fmaf(o1raw[(size_t)n * 256 + f], sb[0][f], sb[1][f]);
      v = v > 0.f ? v : expm1f(v);
    }
    rows[r][f] = v;
  }
  __syncthreads();
  const float* r0 = rows[8 * wv + 0];
  const float* r1 = rows[8 * wv + 1];
  const float* r2 = rows[8 * wv + 2];
  const float* r3 = rows[8 * wv + 3];
  const float* r4 = rows[8 * wv + 4];
  const float* r5 = rows[8 * wv + 5];
  const float* r6 = rows[8 * wv + 6];
  const float* r7 = rows[8 * wv + 7];
  float a0 = 0.f, a1 = 0.f, a2 = 0.f, a3 = 0.f;
  float a4 = 0.f, a5 = 0.f, a6 = 0.f, a7 = 0.f;
#pragma unroll 4
  for (int k = 0; k < 256; ++k) {
    float w2v = W2[k * 64 + lane];   // global, coalesced, L2-resident
    a0 = fmaf(r0[k], w2v, a0);
    a1 = fmaf(r1[k], w2v, a1);
    a2 = fmaf(r2[k], w2v, a2);
    a3 = fmaf(r3[k], w2v, a3);
    a4 = fmaf(r4[k], w2v, a4);
    a5 = fmaf(r5[k], w2v, a5);
    a6 = fmaf(r6[k], w2v, a6);
    a7 = fmaf(r7[k], w2v, a7);
  }
#pragma unroll
  for (int r = 0; r < 8; ++r) {
    float acc = r == 0 ? a0 : r == 1 ? a1 : r == 2 ? a2 : r == 3 ? a3
              : r == 4 ? a4 : r == 5 ? a5 : r == 6 ? a6 : a7;
    int n = base + 8 * wv + r;
    if (n < N) {
      h2[(size_t)n * 64 + lane] = acc;
      float ps = acc * asv;
      float pd = acc * adv;
#pragma unroll
      for (int m = 16; m; m >>= 1) {
        ps += __shfl_xor(ps, m);
        pd += __shfl_xor(pd, m);
      }
      if (c == 0) {
        a_src2[(size_t)n * 2 + g] = ps;
        a_dst2[(size_t)n * 2 + g] = pd;
      }
    }
  }
}

// Fused layer-2 aggregate + head-mean + b2 + ELU + Wc dot + bc.
__global__ __launch_bounds__(256) void kagg2_head(
    const float* __restrict__ h2, const float* __restrict__ as2,
    const float* __restrict__ ad2, const int* __restrict__ rowptr,
    const int* __restrict__ csrs, const float* __restrict__ b2,
    const float* __restrict__ Wc, const float* __restrict__ bc,
    float* __restrict__ out, int N) {
  int wv = threadIdx.x >> 6, lane = threadIdx.x & 63;
  int d = blockIdx.x * 4 + wv;
  if (d >= N) return;
  int r0 = rowptr[d], r1 = rowptr[d + 1];
  float2 adv = *(const float2*)(ad2 + (size_t)d * 2);
  int head = lane >> 5;
  float fa = 0.f, s0 = 0.f, s1 = 0.f;
  for (int base = r0; base < r1; base += 64) {
    int cd = min(64, r1 - base);
    int s = 0;
    float e0 = 0.f, e1 = 0.f;
    if (lane < cd) {
      s = csrs[base + lane];
      float2 av = *(const float2*)(as2 + (size_t)s * 2);
      float l0 = av.x + adv.x; l0 = l0 >= 0.f ? l0 : NEG_SLOPE * l0;
      float l1 = av.y + adv.y; l1 = l1 >= 0.f ? l1 : NEG_SLOPE * l1;
      e0 = __expf(l0); e1 = __expf(l1);
      s0 += e0; s1 += e1;
    }
    for (int k = 0; k < cd; ++k) {
      int sk = __shfl(s, k);
      float w0 = __shfl(e0, k), w1 = __shfl(e1, k);
      float v = h2[(size_t)sk * 64 + lane];
      fa = fmaf(head ? w1 : w0, v, fa);
    }
  }
#pragma unroll
  for (int m = 32; m; m >>= 1) {
    s0 += __shfl_xor(s0, m);
    s1 += __shfl_xor(s1, m);
  }
  float o2v = fa / (head ? s1 : s0);
  float partner = __shfl_xor(o2v, 32);
  if (lane < 32) {
    float m = 0.5f * (o2v + partner) + b2[lane];
    m = m > 0.f ? m : expm1f(m);
    float t = m * Wc[lane];
#pragma unroll
    for (int mk = 16; mk; mk >>= 1) t += __shfl_xor(t, mk);
    if (lane == 0) out[d] = t + bc[0];
  }
}

extern "C" void kernel_launch(void* const* d_in, const int* in_sizes, int n_in,
                              void* d_out, int out_size, void* d_ws, size_t ws_size,
                              hipStream_t stream) {
  const float* x = (const float*)d_in[0];
  const int* ei = (const int*)d_in[1];
  const float* W1 = (const float*)d_in[2];
  const float* as1w = (const float*)d_in[3];
  const float* ad1w = (const float*)d_in[4];
  // d_in[5] = b1: cancels exactly under BatchNorm -> unused
  const float* gamma1 = (const float*)d_in[6];
  const float* beta1 = (const float*)d_in[7];
  const float* W2 = (const float*)d_in[8];
  const float* as2w = (const float*)d_in[9];
  const float* ad2w = (const float*)d_in[10];
  const float* b2 = (const float*)d_in[11];
  const float* Wc = (const float*)d_in[12];
  const float* bc = (const float*)d_in[13];

  const int N = in_sizes[0] / 13;
  const int E = in_sizes[1] / 2;
  const int Et = E + N;  // + self loops
  const int* srcp = ei;
  const int* dstp = ei + E;

  float* ws = (float*)d_ws;
  float* O1 = ws;                                // N*256 (raw, pre-BN)
  float* Y = O1 + (size_t)N * 256;               // N*52
  float* AS1 = Y + (size_t)N * 52;               // N*4 (16B aligned)
  float* AD1 = AS1 + (size_t)N * 4;              // N*4
  float* H2 = AD1 + (size_t)N * 4;               // N*64
  float* AS2 = H2 + (size_t)N * 64;              // N*2
  float* AD2 = AS2 + (size_t)N * 2;              // N*2
  float* CS = AD2 + (size_t)N * 2;               // 64 (52 used)
  float* CD = CS + 64;                           // 64
  float* BNS = CD + 64;                          // 256
  float* BNQ = BNS + 256;                        // 256
  int* ROWPTR = (int*)(BNQ + 256);               // N+1
  int* CURS = ROWPTR + (N + 1);                  // N
  int* CSRS = CURS + N;                          // Et
  int* BLKSUM = CSRS + Et;                       // <=1024

  // zero the atomic accumulators (ws is re-poisoned before every launch)
  hipMemsetAsync(CURS, 0, (size_t)N * sizeof(int), stream);
  hipMemsetAsync(BNS, 0, 512 * sizeof(float), stream);

  int eb = (Et + 255) / 256;
  int nbs = (N + 1023) / 1024;
  // CSR build (shared by both layers); hierarchical 3-pass scan
  kc_hist<<<eb, 256, 0, stream>>>(dstp, CURS, E, Et);
  kc_scan1<<<nbs, 1024, 0, stream>>>(CURS, ROWPTR, BLKSUM, N);
  kc_scan2<<<1, 1024, 0, stream>>>(BLKSUM, nbs);
  kc_scan3<<<nbs, 1024, 0, stream>>>(ROWPTR, CURS, BLKSUM, N, Et);
  kc_scatter<<<eb, 256, 0, stream>>>(srcp, dstp, CURS, CSRS, E, Et);

  // layer 1 (h1 never materialized)
  kp_proj<<<1, 64, 0, stream>>>(W1, as1w, ad1w, CS, CD);
  ka_logits<<<(N + 255) / 256, 256, 0, stream>>>(x, CS, CD, AS1, AD1, N);
  agg_x<<<(N + 3) / 4, 256, 0, stream>>>(x, AS1, AD1, ROWPTR, CSRS, Y, N);
  k1b_dense<<<1024, 256, 0, stream>>>(Y, W1, O1, BNS, BNQ, N);

  // layer 2: fused BN+ELU+GEMM (k6 eliminated), W2 from global
  k67_bn_gemm<<<(N + 31) / 32, 256, 0, stream>>>(O1, BNS, BNQ, gamma1, beta1,
                                                 W2, as2w, ad2w, H2, AS2, AD2,
                                                 N, 1.0f / (float)N);
  kagg2_head<<<(N + 3) / 4, 256, 0, stream>>>(H2, AS2, AD2, ROWPTR, CSRS,
                                              b2, Wc, bc, (float*)d_out, N);
}